// Round 1
// baseline (5999.667 us; speedup 1.0000x reference)
//
#include <hip/hip_runtime.h>
#include <cstddef>
#include <cstdint>
#include <cmath>

#define D_MODEL 2048
#define DICT    32768
#define KTOP    32
#define NROWS   2048

#define BM 128
#define BN 128
#define BK 16

// ---------------------------------------------------------------------------
// Encoder: C[n][f] = sum_k A[n][k] * B[f][k] + bias[f]
// A = x [NROWS][D_MODEL], B = We [DICT][D_MODEL]  (both K-major -> "NT" GEMM)
// fp32 vector-ALU GEMM, 128x128 tile, BK=16, 256 threads, 8x8 per thread.
// ---------------------------------------------------------------------------
__global__ __launch_bounds__(256) void encoder_gemm(
    const float* __restrict__ A,
    const float* __restrict__ B,
    const float* __restrict__ bias,
    float* __restrict__ C)
{
    __shared__ float As[BK][BM];   // k-major so fragment reads are contiguous
    __shared__ float Bs[BK][BN];

    const int m0 = blockIdx.y * BM;
    const int n0 = blockIdx.x * BN;
    const int t  = threadIdx.x;
    const int tm = t >> 4;   // 0..15
    const int tn = t & 15;   // 0..15

    float acc[8][8];
    #pragma unroll
    for (int i = 0; i < 8; ++i)
        #pragma unroll
        for (int j = 0; j < 8; ++j) acc[i][j] = 0.f;

    for (int k0 = 0; k0 < D_MODEL; k0 += BK) {
        // stage A-tile and B-tile (each 128x16 floats), transpose into k-major
        #pragma unroll
        for (int e = t; e < (BM * BK) / 4; e += 256) {
            const int row = e >> 2;          // 0..127
            const int kq  = (e & 3) << 2;    // 0,4,8,12
            float4 va = *reinterpret_cast<const float4*>(
                &A[(size_t)(m0 + row) * D_MODEL + k0 + kq]);
            As[kq + 0][row] = va.x; As[kq + 1][row] = va.y;
            As[kq + 2][row] = va.z; As[kq + 3][row] = va.w;
            float4 vb = *reinterpret_cast<const float4*>(
                &B[(size_t)(n0 + row) * D_MODEL + k0 + kq]);
            Bs[kq + 0][row] = vb.x; Bs[kq + 1][row] = vb.y;
            Bs[kq + 2][row] = vb.z; Bs[kq + 3][row] = vb.w;
        }
        __syncthreads();

        #pragma unroll
        for (int k = 0; k < BK; ++k) {
            float a[8], b[8];
            *reinterpret_cast<float4*>(&a[0]) =
                *reinterpret_cast<const float4*>(&As[k][tm * 8]);
            *reinterpret_cast<float4*>(&a[4]) =
                *reinterpret_cast<const float4*>(&As[k][tm * 8 + 4]);
            *reinterpret_cast<float4*>(&b[0]) =
                *reinterpret_cast<const float4*>(&Bs[k][tn * 8]);
            *reinterpret_cast<float4*>(&b[4]) =
                *reinterpret_cast<const float4*>(&Bs[k][tn * 8 + 4]);
            #pragma unroll
            for (int i = 0; i < 8; ++i)
                #pragma unroll
                for (int j = 0; j < 8; ++j)
                    acc[i][j] = fmaf(a[i], b[j], acc[i][j]);
        }
        __syncthreads();
    }

    // epilogue: add bias, vectorized store
    float4 bia0 = *reinterpret_cast<const float4*>(&bias[n0 + tn * 8]);
    float4 bia1 = *reinterpret_cast<const float4*>(&bias[n0 + tn * 8 + 4]);
    #pragma unroll
    for (int i = 0; i < 8; ++i) {
        const int row = m0 + tm * 8 + i;
        float4 o0, o1;
        o0.x = acc[i][0] + bia0.x; o0.y = acc[i][1] + bia0.y;
        o0.z = acc[i][2] + bia0.z; o0.w = acc[i][3] + bia0.w;
        o1.x = acc[i][4] + bia1.x; o1.y = acc[i][5] + bia1.y;
        o1.z = acc[i][6] + bia1.z; o1.w = acc[i][7] + bia1.w;
        float* dst = &C[(size_t)row * DICT + n0 + tn * 8];
        *reinterpret_cast<float4*>(dst)     = o0;
        *reinterpret_cast<float4*>(dst + 4) = o1;
    }
}

// ---------------------------------------------------------------------------
// Top-K per row. One block per row; whole row lives in LDS (128 KB dynamic).
// Iterative extraction with per-thread cached argmax: after removing the
// winner, only the owning thread (winner % 256) rescans its strided slice.
// Ties broken toward smaller index (matches lax.top_k).
// ---------------------------------------------------------------------------
__global__ __launch_bounds__(256) void topk_kernel(
    const float* __restrict__ pre,       // [NROWS][DICT]
    float* __restrict__ features,        // [NROWS][DICT], pre-zeroed
    float* __restrict__ vals_out,        // [NROWS][KTOP]  (relu'd)
    int*   __restrict__ idx_out)         // [NROWS][KTOP]
{
    extern __shared__ float row[];       // DICT floats
    __shared__ float rv4[4];
    __shared__ int   ri4[4];

    const int n = blockIdx.x;
    const int t = threadIdx.x;
    const float* src = pre + (size_t)n * DICT;

    for (int i = t; i < DICT / 4; i += 256)
        reinterpret_cast<float4*>(row)[i] =
            reinterpret_cast<const float4*>(src)[i];
    __syncthreads();

    // initial per-thread best over strided slice
    float best = -INFINITY; int bi = t;
    for (int i = t; i < DICT; i += 256) {
        float v = row[i];
        if (v > best) { best = v; bi = i; }
    }

    for (int r = 0; r < KTOP; ++r) {
        // wave butterfly reduce (val, idx), tie -> smaller idx
        float v = best; int i = bi;
        #pragma unroll
        for (int s = 1; s < 64; s <<= 1) {
            float ov = __shfl_xor(v, s);
            int   oi = __shfl_xor(i, s);
            if (ov > v || (ov == v && oi < i)) { v = ov; i = oi; }
        }
        if ((t & 63) == 0) { rv4[t >> 6] = v; ri4[t >> 6] = i; }
        __syncthreads();
        float gv = rv4[0]; int gi = ri4[0];
        #pragma unroll
        for (int q = 1; q < 4; ++q) {
            float qv = rv4[q]; int qi = ri4[q];
            if (qv > gv || (qv == gv && qi < gi)) { gv = qv; gi = qi; }
        }
        if (t == 0) {
            float rvv = gv > 0.f ? gv : 0.f;   // relu
            features[(size_t)n * DICT + gi] = rvv;
            vals_out[n * KTOP + r] = rvv;
            idx_out[n * KTOP + r]  = gi;
        }
        __syncthreads();   // rv4/ri4 consumed by all before reuse
        // owner removes winner and rescans its slice
        if ((gi & 255) == t) {
            row[gi] = -INFINITY;
            best = -INFINITY; bi = t;
            for (int i2 = t; i2 < DICT; i2 += 256) {
                float vv = row[i2];
                if (vv > best) { best = vv; bi = i2; }
            }
        }
        __syncthreads();
    }
}

// ---------------------------------------------------------------------------
// Decoder: recon[n][d] = bd[d] + sum_k vals[n][k] * Wd[d][idx[n][k]]
// One block per d; Wd row d (contiguous 128 KB) staged in LDS; threads sweep n.
// ---------------------------------------------------------------------------
__global__ __launch_bounds__(256) void decoder_kernel(
    const float* __restrict__ Wd,        // [D_MODEL][DICT]
    const float* __restrict__ bd,        // [D_MODEL]
    const float* __restrict__ vals,      // [NROWS][KTOP]
    const int*   __restrict__ idxs,      // [NROWS][KTOP]
    float* __restrict__ recon)           // [NROWS][D_MODEL]
{
    extern __shared__ float wrow[];      // DICT floats
    const int d = blockIdx.x;
    const int t = threadIdx.x;
    const float* src = Wd + (size_t)d * DICT;

    for (int i = t; i < DICT / 4; i += 256)
        reinterpret_cast<float4*>(wrow)[i] =
            reinterpret_cast<const float4*>(src)[i];
    __syncthreads();

    const float b = bd[d];
    for (int n = t; n < NROWS; n += 256) {
        const float* v  = vals + n * KTOP;
        const int*   ix = idxs + n * KTOP;
        float acc = b;
        #pragma unroll
        for (int k = 0; k < KTOP; ++k)
            acc = fmaf(v[k], wrow[ix[k]], acc);
        recon[(size_t)n * D_MODEL + d] = acc;
    }
}

// ---------------------------------------------------------------------------
extern "C" void kernel_launch(void* const* d_in, const int* in_sizes, int n_in,
                              void* d_out, int out_size, void* d_ws, size_t ws_size,
                              hipStream_t stream)
{
    const float* x  = (const float*)d_in[0];
    const float* We = (const float*)d_in[1];
    const float* be = (const float*)d_in[2];
    const float* Wd = (const float*)d_in[3];
    const float* bd = (const float*)d_in[4];

    float* out      = (float*)d_out;
    float* recon    = out;                                        // [N][D]
    float* features = out + (size_t)NROWS * D_MODEL;              // [N][DICT]
    float* pre      = features + (size_t)NROWS * DICT;            // [N][DICT]

    float* ws_vals = (float*)d_ws;                                // [N][KTOP]
    int*   ws_idx  = (int*)((char*)d_ws + (size_t)NROWS * KTOP * 4);

    // zero the dense features output (scatter fills only top-k entries)
    hipMemsetAsync(features, 0, (size_t)NROWS * DICT * sizeof(float), stream);

    // 1) encoder GEMM -> pre_acts
    dim3 ggrid(DICT / BN, NROWS / BM);
    encoder_gemm<<<ggrid, 256, 0, stream>>>(x, We, be, pre);

    // 2) top-k + relu + scatter
    topk_kernel<<<NROWS, 256, DICT * sizeof(float), stream>>>(
        pre, features, ws_vals, ws_idx);

    // 3) sparse decoder
    decoder_kernel<<<D_MODEL, 256, DICT * sizeof(float), stream>>>(
        Wd, bd, ws_vals, ws_idx, recon);
}

// Round 2
// 3995.993 us; speedup vs baseline: 1.5014x; 1.5014x over previous
//
#include <hip/hip_runtime.h>
#include <cstddef>
#include <cstdint>
#include <cmath>

#define D_MODEL 2048
#define DICT    32768
#define KTOP    32
#define NROWS   2048
#define NCAND   40          // approx top-k margin; exact top-32 recomputed from these
#define NKSTEP  (D_MODEL / 32)

typedef float    f32x4  __attribute__((ext_vector_type(4)));
typedef __bf16   bf16x8 __attribute__((ext_vector_type(8)));
typedef unsigned short us8 __attribute__((ext_vector_type(8)));
typedef unsigned short us4 __attribute__((ext_vector_type(4)));

__device__ __forceinline__ unsigned short f2bf_rne(float f) {
    unsigned u = __builtin_bit_cast(unsigned, f);
    unsigned r = u + 0x7fffu + ((u >> 16) & 1u);
    return (unsigned short)(r >> 16);
}
__device__ __forceinline__ float bf2f(unsigned short h) {
    unsigned u = ((unsigned)h) << 16;
    return __builtin_bit_cast(float, u);
}

// ---------------------------------------------------------------------------
// Encoder: pre[n][f] = x[n][:]·We[f][:] + be[f], via 3-term bf16-split MFMA.
// 128x128 tile, BK=32, 4 waves (2x2), 16x16x32 bf16 MFMA, reg-staged LDS with
// XOR swizzle (byte ^= (row&7)<<4) so ds_read_b128 fragments are conflict-free.
// ---------------------------------------------------------------------------
__global__ __launch_bounds__(256) void encoder_mfma(
    const float* __restrict__ A,      // x  [NROWS][D_MODEL]
    const float* __restrict__ B,      // We [DICT][D_MODEL]
    const float* __restrict__ bias,   // be [DICT]
    float* __restrict__ C)            // pre [NROWS][DICT]
{
    __shared__ __align__(16) unsigned short Ah[128 * 32];
    __shared__ __align__(16) unsigned short Al[128 * 32];
    __shared__ __align__(16) unsigned short Bh[128 * 32];
    __shared__ __align__(16) unsigned short Bl[128 * 32];

    const int t    = threadIdx.x;
    const int m0   = blockIdx.y * 128;
    const int n0   = blockIdx.x * 128;
    const int lane = t & 63;
    const int wid  = t >> 6;
    const int wr   = wid >> 1;          // wave row (0..1), owns 64 rows
    const int wc   = wid & 1;           // wave col (0..1), owns 64 cols

    // staging map: chunk c = t + 256*j -> row=c>>3 (0..127), kq=(c&7)*4
    int srow[4], soff[4];
    const float* pa_src[4];
    const float* pb_src[4];
    #pragma unroll
    for (int j = 0; j < 4; ++j) {
        const int c = t + 256 * j;
        srow[j] = c >> 3;
        const int kq = (c & 7) * 4;
        soff[j] = (srow[j] * 32 + kq) ^ ((srow[j] & 7) << 3);   // ushort units
        pa_src[j] = A + (size_t)(m0 + srow[j]) * D_MODEL + kq;
        pb_src[j] = B + (size_t)(n0 + srow[j]) * D_MODEL + kq;
    }

    float4 pa[4], pb[4];
    #pragma unroll
    for (int j = 0; j < 4; ++j) {
        pa[j] = *reinterpret_cast<const float4*>(pa_src[j]);
        pb[j] = *reinterpret_cast<const float4*>(pb_src[j]);
    }

    f32x4 acc[4][4];
    #pragma unroll
    for (int i = 0; i < 4; ++i)
        #pragma unroll
        for (int j = 0; j < 4; ++j) acc[i][j] = (f32x4)0.f;

    for (int kt = 0; kt < NKSTEP; ++kt) {
        // convert + LDS write (hi/lo split)
        #pragma unroll
        for (int j = 0; j < 4; ++j) {
            float va[4] = {pa[j].x, pa[j].y, pa[j].z, pa[j].w};
            float vb[4] = {pb[j].x, pb[j].y, pb[j].z, pb[j].w};
            us4 ah, al, bh, bl;
            #pragma unroll
            for (int e = 0; e < 4; ++e) {
                ah[e] = f2bf_rne(va[e]);
                al[e] = f2bf_rne(va[e] - bf2f(ah[e]));
                bh[e] = f2bf_rne(vb[e]);
                bl[e] = f2bf_rne(vb[e] - bf2f(bh[e]));
            }
            *reinterpret_cast<us4*>(&Ah[soff[j]]) = ah;
            *reinterpret_cast<us4*>(&Al[soff[j]]) = al;
            *reinterpret_cast<us4*>(&Bh[soff[j]]) = bh;
            *reinterpret_cast<us4*>(&Bl[soff[j]]) = bl;
        }
        __syncthreads();

        // prefetch next K-tile while MFMAs run
        if (kt + 1 < NKSTEP) {
            const int ko = (kt + 1) * 32;
            #pragma unroll
            for (int j = 0; j < 4; ++j) {
                pa[j] = *reinterpret_cast<const float4*>(pa_src[j] + ko);
                pb[j] = *reinterpret_cast<const float4*>(pb_src[j] + ko);
            }
        }

        // B fragments (hi+lo)
        bf16x8 fbh[4], fbl[4];
        #pragma unroll
        for (int j = 0; j < 4; ++j) {
            const int r = wc * 64 + j * 16 + (lane & 15);
            const int o = (r * 32 + ((lane >> 4) * 8)) ^ ((r & 7) << 3);
            fbh[j] = __builtin_bit_cast(bf16x8, *reinterpret_cast<const us8*>(&Bh[o]));
            fbl[j] = __builtin_bit_cast(bf16x8, *reinterpret_cast<const us8*>(&Bl[o]));
        }
        #pragma unroll
        for (int i = 0; i < 4; ++i) {
            const int r = wr * 64 + i * 16 + (lane & 15);
            const int o = (r * 32 + ((lane >> 4) * 8)) ^ ((r & 7) << 3);
            bf16x8 fah = __builtin_bit_cast(bf16x8, *reinterpret_cast<const us8*>(&Ah[o]));
            bf16x8 fal = __builtin_bit_cast(bf16x8, *reinterpret_cast<const us8*>(&Al[o]));
            #pragma unroll
            for (int j = 0; j < 4; ++j)
                acc[i][j] = __builtin_amdgcn_mfma_f32_16x16x32_bf16(fah, fbh[j], acc[i][j], 0, 0, 0);
            #pragma unroll
            for (int j = 0; j < 4; ++j)
                acc[i][j] = __builtin_amdgcn_mfma_f32_16x16x32_bf16(fah, fbl[j], acc[i][j], 0, 0, 0);
            #pragma unroll
            for (int j = 0; j < 4; ++j)
                acc[i][j] = __builtin_amdgcn_mfma_f32_16x16x32_bf16(fal, fbh[j], acc[i][j], 0, 0, 0);
        }
        __syncthreads();
    }

    // epilogue: D layout col=lane&15, row=(lane>>4)*4+reg
    #pragma unroll
    for (int j = 0; j < 4; ++j) {
        const int col = n0 + wc * 64 + j * 16 + (lane & 15);
        const float bv = bias[col];
        #pragma unroll
        for (int i = 0; i < 4; ++i) {
            const int rowb = m0 + wr * 64 + i * 16 + ((lane >> 4) * 4);
            #pragma unroll
            for (int r = 0; r < 4; ++r)
                C[(size_t)(rowb + r) * DICT + col] = acc[i][j][r] + bv;
        }
    }
}

// ---------------------------------------------------------------------------
// Approx top-NCAND candidate indices per row (iterative extraction in LDS).
// ---------------------------------------------------------------------------
__global__ __launch_bounds__(256) void topk_cand_kernel(
    const float* __restrict__ pre,       // [NROWS][DICT] (approx)
    int* __restrict__ cand_idx)          // [NROWS][NCAND]
{
    extern __shared__ float row[];       // DICT floats
    __shared__ float rv4[4];
    __shared__ int   ri4[4];

    const int n = blockIdx.x;
    const int t = threadIdx.x;
    const float* src = pre + (size_t)n * DICT;

    for (int i = t; i < DICT / 4; i += 256)
        reinterpret_cast<float4*>(row)[i] =
            reinterpret_cast<const float4*>(src)[i];
    __syncthreads();

    float best = -INFINITY; int bi = t;
    for (int i = t; i < DICT; i += 256) {
        float v = row[i];
        if (v > best) { best = v; bi = i; }
    }

    for (int r = 0; r < NCAND; ++r) {
        float v = best; int i = bi;
        #pragma unroll
        for (int s = 1; s < 64; s <<= 1) {
            float ov = __shfl_xor(v, s);
            int   oi = __shfl_xor(i, s);
            if (ov > v || (ov == v && oi < i)) { v = ov; i = oi; }
        }
        if ((t & 63) == 0) { rv4[t >> 6] = v; ri4[t >> 6] = i; }
        __syncthreads();
        float gv = rv4[0]; int gi = ri4[0];
        #pragma unroll
        for (int q = 1; q < 4; ++q) {
            float qv = rv4[q]; int qi = ri4[q];
            if (qv > gv || (qv == gv && qi < gi)) { gv = qv; gi = qi; }
        }
        if (t == 0) cand_idx[n * NCAND + r] = gi;
        __syncthreads();
        if ((gi & 255) == t) {
            row[gi] = -INFINITY;
            best = -INFINITY; bi = t;
            for (int i2 = t; i2 < DICT; i2 += 256) {
                float vv = row[i2];
                if (vv > best) { best = vv; bi = i2; }
            }
        }
        __syncthreads();
    }
}

// ---------------------------------------------------------------------------
// Exact recompute of the NCAND candidate dot products in f32, exact top-32
// selection, relu, scatter into dense features, write (vals, idx) for decoder.
// One block per row; 4 waves; candidates round-robined across waves.
// ---------------------------------------------------------------------------
__global__ __launch_bounds__(256) void recompute_select_kernel(
    const float* __restrict__ x,         // [NROWS][D_MODEL]
    const float* __restrict__ We,        // [DICT][D_MODEL]
    const float* __restrict__ be,        // [DICT]
    const int*   __restrict__ cand_idx,  // [NROWS][NCAND]
    float* __restrict__ features,        // [NROWS][DICT], pre-zeroed
    float* __restrict__ vals_out,        // [NROWS][KTOP]
    int*   __restrict__ idx_out)         // [NROWS][KTOP]
{
    __shared__ float xr[D_MODEL];
    __shared__ float cv[NCAND];
    __shared__ int   ci[NCAND];

    const int n    = blockIdx.x;
    const int t    = threadIdx.x;
    const int lane = t & 63;
    const int w    = t >> 6;

    for (int i = t; i < D_MODEL / 4; i += 256)
        reinterpret_cast<float4*>(xr)[i] =
            reinterpret_cast<const float4*>(x + (size_t)n * D_MODEL)[i];
    if (t < NCAND) ci[t] = cand_idx[n * NCAND + t];
    __syncthreads();

    for (int c = w; c < NCAND; c += 4) {
        const int idx = ci[c];
        const float4* wrow = reinterpret_cast<const float4*>(We + (size_t)idx * D_MODEL);
        const float4* xro  = reinterpret_cast<const float4*>(xr);
        float s = 0.f;
        #pragma unroll
        for (int p = 0; p < 8; ++p) {
            float4 a = xro[lane + 64 * p];
            float4 b = wrow[lane + 64 * p];
            s = fmaf(a.x, b.x, s); s = fmaf(a.y, b.y, s);
            s = fmaf(a.z, b.z, s); s = fmaf(a.w, b.w, s);
        }
        #pragma unroll
        for (int sh = 1; sh < 64; sh <<= 1) s += __shfl_xor(s, sh);
        if (lane == 0) cv[c] = s + be[idx];
    }
    __syncthreads();

    if (w == 0) {
        float v = (lane < NCAND) ? cv[lane] : -INFINITY;
        int   id = (lane < NCAND) ? ci[lane] : 0x7fffffff;
        for (int r = 0; r < KTOP; ++r) {
            float bv = v; int bi = id; int bl = lane;
            #pragma unroll
            for (int s = 1; s < 64; s <<= 1) {
                float ov = __shfl_xor(bv, s);
                int   oi = __shfl_xor(bi, s);
                int   ol = __shfl_xor(bl, s);
                if (ov > bv || (ov == bv && oi < bi)) { bv = ov; bi = oi; bl = ol; }
            }
            if (lane == bl) v = -INFINITY;
            if (lane == 0) {
                float rv = bv > 0.f ? bv : 0.f;
                vals_out[n * KTOP + r] = rv;
                idx_out[n * KTOP + r]  = bi;
                features[(size_t)n * DICT + bi] = rv;
            }
        }
    }
}

// ---------------------------------------------------------------------------
// Decoder: recon[n][d] = bd[d] + sum_k vals[n][k] * Wd[d][idx[n][k]]
// ---------------------------------------------------------------------------
__global__ __launch_bounds__(256) void decoder_kernel(
    const float* __restrict__ Wd,        // [D_MODEL][DICT]
    const float* __restrict__ bd,        // [D_MODEL]
    const float* __restrict__ vals,      // [NROWS][KTOP]
    const int*   __restrict__ idxs,      // [NROWS][KTOP]
    float* __restrict__ recon)           // [NROWS][D_MODEL]
{
    extern __shared__ float wrow[];      // DICT floats
    const int d = blockIdx.x;
    const int t = threadIdx.x;
    const float* src = Wd + (size_t)d * DICT;

    for (int i = t; i < DICT / 4; i += 256)
        reinterpret_cast<float4*>(wrow)[i] =
            reinterpret_cast<const float4*>(src)[i];
    __syncthreads();

    const float b = bd[d];
    for (int n = t; n < NROWS; n += 256) {
        const float* v  = vals + n * KTOP;
        const int*   ix = idxs + n * KTOP;
        float acc = b;
        #pragma unroll
        for (int k = 0; k < KTOP; ++k)
            acc = fmaf(v[k], wrow[ix[k]], acc);
        recon[(size_t)n * D_MODEL + d] = acc;
    }
}

// ---------------------------------------------------------------------------
extern "C" void kernel_launch(void* const* d_in, const int* in_sizes, int n_in,
                              void* d_out, int out_size, void* d_ws, size_t ws_size,
                              hipStream_t stream)
{
    const float* x  = (const float*)d_in[0];
    const float* We = (const float*)d_in[1];
    const float* be = (const float*)d_in[2];
    const float* Wd = (const float*)d_in[3];
    const float* bd = (const float*)d_in[4];

    float* out      = (float*)d_out;
    float* recon    = out;                                        // [N][D]
    float* features = out + (size_t)NROWS * D_MODEL;              // [N][DICT]
    float* pre      = features + (size_t)NROWS * DICT;            // [N][DICT]

    char* ws = (char*)d_ws;
    int*   ws_cand = (int*)ws;                                    // [N][NCAND]
    float* ws_vals = (float*)(ws + (size_t)NROWS * NCAND * 4);    // [N][KTOP]
    int*   ws_idx  = (int*)(ws + (size_t)NROWS * NCAND * 4
                               + (size_t)NROWS * KTOP * 4);       // [N][KTOP]

    hipMemsetAsync(features, 0, (size_t)NROWS * DICT * sizeof(float), stream);

    // 1) encoder GEMM (3-term bf16-split MFMA) -> approx pre_acts
    dim3 ggrid(DICT / 128, NROWS / 128);
    encoder_mfma<<<ggrid, 256, 0, stream>>>(x, We, be, pre);

    // 2) approx top-NCAND candidates
    topk_cand_kernel<<<NROWS, 256, DICT * sizeof(float), stream>>>(pre, ws_cand);

    // 3) exact recompute of candidates + exact top-32 + scatter
    recompute_select_kernel<<<NROWS, 256, 0, stream>>>(
        x, We, be, ws_cand, features, ws_vals, ws_idx);

    // 4) sparse decoder
    decoder_kernel<<<D_MODEL, 256, DICT * sizeof(float), stream>>>(
        Wd, bd, ws_vals, ws_idx, recon);
}

// Round 3
// 1622.891 us; speedup vs baseline: 3.6969x; 2.4623x over previous
//
#include <hip/hip_runtime.h>
#include <cstddef>
#include <cstdint>
#include <cmath>

#define D_MODEL 2048
#define DICT    32768
#define KTOP    32
#define NROWS   2048
#define NCAND_MIN 40        // candidate margin over KTOP (guards bf16-split error)
#define CAPMAX  256         // max candidates kept per row
#define NKSTEP  (D_MODEL / 32)

typedef float    f32x4  __attribute__((ext_vector_type(4)));
typedef __bf16   bf16x8 __attribute__((ext_vector_type(8)));
typedef unsigned short us8 __attribute__((ext_vector_type(8)));
typedef unsigned short us4 __attribute__((ext_vector_type(4)));

__device__ __forceinline__ unsigned short f2bf_rne(float f) {
    unsigned u = __builtin_bit_cast(unsigned, f);
    unsigned r = u + 0x7fffu + ((u >> 16) & 1u);
    return (unsigned short)(r >> 16);
}
__device__ __forceinline__ float bf2f(unsigned short h) {
    unsigned u = ((unsigned)h) << 16;
    return __builtin_bit_cast(float, u);
}

// ---------------------------------------------------------------------------
// Encoder: pre[n][f] = x[n][:]·We[f][:] + be[f], via 3-term bf16-split MFMA.
// ---------------------------------------------------------------------------
__global__ __launch_bounds__(256) void encoder_mfma(
    const float* __restrict__ A,
    const float* __restrict__ B,
    const float* __restrict__ bias,
    float* __restrict__ C)
{
    __shared__ __align__(16) unsigned short Ah[128 * 32];
    __shared__ __align__(16) unsigned short Al[128 * 32];
    __shared__ __align__(16) unsigned short Bh[128 * 32];
    __shared__ __align__(16) unsigned short Bl[128 * 32];

    const int t    = threadIdx.x;
    const int m0   = blockIdx.y * 128;
    const int n0   = blockIdx.x * 128;
    const int lane = t & 63;
    const int wid  = t >> 6;
    const int wr   = wid >> 1;
    const int wc   = wid & 1;

    int srow[4], soff[4];
    const float* pa_src[4];
    const float* pb_src[4];
    #pragma unroll
    for (int j = 0; j < 4; ++j) {
        const int c = t + 256 * j;
        srow[j] = c >> 3;
        const int kq = (c & 7) * 4;
        soff[j] = (srow[j] * 32 + kq) ^ ((srow[j] & 7) << 3);
        pa_src[j] = A + (size_t)(m0 + srow[j]) * D_MODEL + kq;
        pb_src[j] = B + (size_t)(n0 + srow[j]) * D_MODEL + kq;
    }

    float4 pa[4], pb[4];
    #pragma unroll
    for (int j = 0; j < 4; ++j) {
        pa[j] = *reinterpret_cast<const float4*>(pa_src[j]);
        pb[j] = *reinterpret_cast<const float4*>(pb_src[j]);
    }

    f32x4 acc[4][4];
    #pragma unroll
    for (int i = 0; i < 4; ++i)
        #pragma unroll
        for (int j = 0; j < 4; ++j) acc[i][j] = (f32x4)0.f;

    for (int kt = 0; kt < NKSTEP; ++kt) {
        #pragma unroll
        for (int j = 0; j < 4; ++j) {
            float va[4] = {pa[j].x, pa[j].y, pa[j].z, pa[j].w};
            float vb[4] = {pb[j].x, pb[j].y, pb[j].z, pb[j].w};
            us4 ah, al, bh, bl;
            #pragma unroll
            for (int e = 0; e < 4; ++e) {
                ah[e] = f2bf_rne(va[e]);
                al[e] = f2bf_rne(va[e] - bf2f(ah[e]));
                bh[e] = f2bf_rne(vb[e]);
                bl[e] = f2bf_rne(vb[e] - bf2f(bh[e]));
            }
            *reinterpret_cast<us4*>(&Ah[soff[j]]) = ah;
            *reinterpret_cast<us4*>(&Al[soff[j]]) = al;
            *reinterpret_cast<us4*>(&Bh[soff[j]]) = bh;
            *reinterpret_cast<us4*>(&Bl[soff[j]]) = bl;
        }
        __syncthreads();

        if (kt + 1 < NKSTEP) {
            const int ko = (kt + 1) * 32;
            #pragma unroll
            for (int j = 0; j < 4; ++j) {
                pa[j] = *reinterpret_cast<const float4*>(pa_src[j] + ko);
                pb[j] = *reinterpret_cast<const float4*>(pb_src[j] + ko);
            }
        }

        bf16x8 fbh[4], fbl[4];
        #pragma unroll
        for (int j = 0; j < 4; ++j) {
            const int r = wc * 64 + j * 16 + (lane & 15);
            const int o = (r * 32 + ((lane >> 4) * 8)) ^ ((r & 7) << 3);
            fbh[j] = __builtin_bit_cast(bf16x8, *reinterpret_cast<const us8*>(&Bh[o]));
            fbl[j] = __builtin_bit_cast(bf16x8, *reinterpret_cast<const us8*>(&Bl[o]));
        }
        #pragma unroll
        for (int i = 0; i < 4; ++i) {
            const int r = wr * 64 + i * 16 + (lane & 15);
            const int o = (r * 32 + ((lane >> 4) * 8)) ^ ((r & 7) << 3);
            bf16x8 fah = __builtin_bit_cast(bf16x8, *reinterpret_cast<const us8*>(&Ah[o]));
            bf16x8 fal = __builtin_bit_cast(bf16x8, *reinterpret_cast<const us8*>(&Al[o]));
            #pragma unroll
            for (int j = 0; j < 4; ++j)
                acc[i][j] = __builtin_amdgcn_mfma_f32_16x16x32_bf16(fah, fbh[j], acc[i][j], 0, 0, 0);
            #pragma unroll
            for (int j = 0; j < 4; ++j)
                acc[i][j] = __builtin_amdgcn_mfma_f32_16x16x32_bf16(fah, fbl[j], acc[i][j], 0, 0, 0);
            #pragma unroll
            for (int j = 0; j < 4; ++j)
                acc[i][j] = __builtin_amdgcn_mfma_f32_16x16x32_bf16(fal, fbh[j], acc[i][j], 0, 0, 0);
        }
        __syncthreads();
    }

    #pragma unroll
    for (int j = 0; j < 4; ++j) {
        const int col = n0 + wc * 64 + j * 16 + (lane & 15);
        const float bv = bias[col];
        #pragma unroll
        for (int i = 0; i < 4; ++i) {
            const int rowb = m0 + wr * 64 + i * 16 + ((lane >> 4) * 4);
            #pragma unroll
            for (int r = 0; r < 4; ++r)
                C[(size_t)(rowb + r) * DICT + col] = acc[i][j][r] + bv;
        }
    }
}

// ---------------------------------------------------------------------------
// Histogram radix-select of candidates (positive values only — ReLU makes
// negative top-k entries output-irrelevant). One block per row.
// Pass 1: 4096-bin LDS histogram of (bits >> 19) for v > 0.
// Suffix-scan finds highest bin with from-top cumulative >= NCAND_MIN.
// Pass 2: compact all indices with bin >= threshold.
// ---------------------------------------------------------------------------
__global__ __launch_bounds__(256) void topk_cand_hist(
    const float* __restrict__ pre,       // [NROWS][DICT]
    int* __restrict__ cand_idx,          // [NROWS][cap]
    int* __restrict__ cand_cnt,          // [NROWS]
    int cap)
{
    __shared__ unsigned hist[4096];
    __shared__ unsigned part[2][256];
    __shared__ int s_thr;
    __shared__ unsigned s_cnt;

    const int n = blockIdx.x;
    const int t = threadIdx.x;
    const float4* src = reinterpret_cast<const float4*>(pre + (size_t)n * DICT);

    for (int i = t; i < 4096; i += 256) hist[i] = 0;
    if (t == 0) { s_thr = -1; s_cnt = 0; }
    __syncthreads();

    #pragma unroll 4
    for (int p = 0; p < DICT / 1024; ++p) {
        float4 v = src[t + 256 * p];
        float e[4] = {v.x, v.y, v.z, v.w};
        #pragma unroll
        for (int j = 0; j < 4; ++j)
            if (e[j] > 0.f)
                atomicAdd(&hist[__builtin_bit_cast(unsigned, e[j]) >> 19], 1u);
    }
    __syncthreads();

    // per-thread partials over 16 bins + block suffix scan (right-to-left)
    unsigned hv[16];
    unsigned local = 0;
    #pragma unroll
    for (int b = 0; b < 16; ++b) { hv[b] = hist[t * 16 + b]; local += hv[b]; }
    part[0][t] = local;
    __syncthreads();
    int sb = 0;
    for (int s = 1; s < 256; s <<= 1) {
        unsigned v2 = part[sb][t];
        if (t + s < 256) v2 += part[sb][t + s];
        part[sb ^ 1][t] = v2;
        sb ^= 1;
        __syncthreads();
    }
    const unsigned above = (t < 255) ? part[sb][t + 1] : 0;

    unsigned cum = above;
    int mybin = -1;
    #pragma unroll
    for (int b = 15; b >= 0; --b) {
        cum += hv[b];
        if (mybin < 0 && cum >= NCAND_MIN) mybin = t * 16 + b;
    }
    if (mybin >= 0) atomicMax(&s_thr, mybin);
    __syncthreads();
    const unsigned thr = (s_thr < 0) ? 0u : (unsigned)s_thr;

    for (int p = 0; p < DICT / 1024; ++p) {
        float4 v = src[t + 256 * p];
        float e[4] = {v.x, v.y, v.z, v.w};
        #pragma unroll
        for (int j = 0; j < 4; ++j) {
            if (e[j] > 0.f &&
                (__builtin_bit_cast(unsigned, e[j]) >> 19) >= thr) {
                unsigned pos = atomicAdd(&s_cnt, 1u);
                if (pos < (unsigned)cap)
                    cand_idx[(size_t)n * cap + pos] = (t + 256 * p) * 4 + j;
            }
        }
    }
    __syncthreads();
    if (t == 0) cand_cnt[n] = (int)min(s_cnt, (unsigned)cap);
}

// ---------------------------------------------------------------------------
// Exact f32 recompute of candidate dots + exact top-32 + relu + scatter.
// ---------------------------------------------------------------------------
__global__ __launch_bounds__(256) void recompute_select_kernel(
    const float* __restrict__ x,
    const float* __restrict__ We,
    const float* __restrict__ be,
    const int*   __restrict__ cand_idx,  // [NROWS][cap]
    const int*   __restrict__ cand_cnt,  // [NROWS]
    int cap,
    float* __restrict__ features,        // pre-zeroed
    float* __restrict__ vals_out,
    int*   __restrict__ idx_out)
{
    __shared__ float xr[D_MODEL];
    __shared__ float cv[CAPMAX];
    __shared__ int   ci[CAPMAX];

    const int n    = blockIdx.x;
    const int t    = threadIdx.x;
    const int lane = t & 63;
    const int w    = t >> 6;
    const int cnt  = cand_cnt[n];

    for (int i = t; i < D_MODEL / 4; i += 256)
        reinterpret_cast<float4*>(xr)[i] =
            reinterpret_cast<const float4*>(x + (size_t)n * D_MODEL)[i];
    for (int c = t; c < cnt; c += 256) ci[c] = cand_idx[(size_t)n * cap + c];
    __syncthreads();

    for (int c = w; c < cnt; c += 4) {
        const int idx = ci[c];
        const float4* wrow = reinterpret_cast<const float4*>(We + (size_t)idx * D_MODEL);
        const float4* xro  = reinterpret_cast<const float4*>(xr);
        float s = 0.f;
        #pragma unroll
        for (int p = 0; p < 8; ++p) {
            float4 a = xro[lane + 64 * p];
            float4 b = wrow[lane + 64 * p];
            s = fmaf(a.x, b.x, s); s = fmaf(a.y, b.y, s);
            s = fmaf(a.z, b.z, s); s = fmaf(a.w, b.w, s);
        }
        #pragma unroll
        for (int sh = 1; sh < 64; sh <<= 1) s += __shfl_xor(s, sh);
        if (lane == 0) cv[c] = s + be[idx];
    }
    __syncthreads();

    if (w == 0) {
        float pv[CAPMAX / 64];
        int   pi[CAPMAX / 64];
        #pragma unroll
        for (int q = 0; q < CAPMAX / 64; ++q) {
            const int c = lane + 64 * q;
            const bool ok = c < cnt;
            pv[q] = ok ? cv[c] : -INFINITY;
            pi[q] = ok ? ci[c] : 0x7fffffff;
        }
        for (int r = 0; r < KTOP; ++r) {
            float bv = pv[0]; int bi = pi[0]; int bq = 0;
            #pragma unroll
            for (int q = 1; q < CAPMAX / 64; ++q)
                if (pv[q] > bv || (pv[q] == bv && pi[q] < bi)) {
                    bv = pv[q]; bi = pi[q]; bq = q;
                }
            float gv = bv; int gi = bi;
            #pragma unroll
            for (int s = 1; s < 64; s <<= 1) {
                float ov = __shfl_xor(gv, s);
                int   oi = __shfl_xor(gi, s);
                if (ov > gv || (ov == gv && oi < gi)) { gv = ov; gi = oi; }
            }
            if (bi == gi) pv[bq] = -INFINITY;   // indices unique -> sole owner
            if (lane == 0) {
                const bool valid = (gi != 0x7fffffff);
                const float rv = (valid && gv > 0.f) ? gv : 0.f;
                vals_out[n * KTOP + r] = rv;
                idx_out[n * KTOP + r]  = valid ? gi : 0;
                if (valid) features[(size_t)n * DICT + gi] = rv;
            }
        }
    }
}

// ---------------------------------------------------------------------------
// Decoder: recon[n][d] = bd[d] + sum_k vals[n][k] * Wd[d][idx[n][k]]
// ---------------------------------------------------------------------------
__global__ __launch_bounds__(256) void decoder_kernel(
    const float* __restrict__ Wd,
    const float* __restrict__ bd,
    const float* __restrict__ vals,
    const int*   __restrict__ idxs,
    float* __restrict__ recon)
{
    extern __shared__ float wrow[];
    const int d = blockIdx.x;
    const int t = threadIdx.x;
    const float* src = Wd + (size_t)d * DICT;

    for (int i = t; i < DICT / 4; i += 256)
        reinterpret_cast<float4*>(wrow)[i] =
            reinterpret_cast<const float4*>(src)[i];
    __syncthreads();

    const float b = bd[d];
    for (int n = t; n < NROWS; n += 256) {
        const float* v  = vals + n * KTOP;
        const int*   ix = idxs + n * KTOP;
        float acc = b;
        #pragma unroll
        for (int k = 0; k < KTOP; ++k)
            acc = fmaf(v[k], wrow[ix[k]], acc);
        recon[(size_t)n * D_MODEL + d] = acc;
    }
}

// ---------------------------------------------------------------------------
extern "C" void kernel_launch(void* const* d_in, const int* in_sizes, int n_in,
                              void* d_out, int out_size, void* d_ws, size_t ws_size,
                              hipStream_t stream)
{
    const float* x  = (const float*)d_in[0];
    const float* We = (const float*)d_in[1];
    const float* be = (const float*)d_in[2];
    const float* Wd = (const float*)d_in[3];
    const float* bd = (const float*)d_in[4];

    float* out      = (float*)d_out;
    float* recon    = out;
    float* features = out + (size_t)NROWS * D_MODEL;
    float* pre      = features + (size_t)NROWS * DICT;

    // candidate cap sized to the workspace (clamped to [48, CAPMAX])
    long cap_l = (long)(ws_size / 4 - (size_t)NROWS * (1 + 2 * KTOP)) / NROWS;
    int cap = (int)(cap_l < 48 ? 48 : (cap_l > CAPMAX ? CAPMAX : cap_l));

    char* ws = (char*)d_ws;
    int*   ws_cand = (int*)ws;                                       // [N][cap]
    int*   ws_cnt  = (int*)(ws + (size_t)NROWS * cap * 4);           // [N]
    float* ws_vals = (float*)(ws + (size_t)NROWS * (cap + 1) * 4);   // [N][K]
    int*   ws_idx  = (int*)(ws + (size_t)NROWS * (cap + 1 + KTOP) * 4);

    hipMemsetAsync(features, 0, (size_t)NROWS * DICT * sizeof(float), stream);

    dim3 ggrid(DICT / 128, NROWS / 128);
    encoder_mfma<<<ggrid, 256, 0, stream>>>(x, We, be, pre);

    topk_cand_hist<<<NROWS, 256, 0, stream>>>(pre, ws_cand, ws_cnt, cap);

    recompute_select_kernel<<<NROWS, 256, 0, stream>>>(
        x, We, be, ws_cand, ws_cnt, cap, features, ws_vals, ws_idx);

    decoder_kernel<<<D_MODEL, 256, DICT * sizeof(float), stream>>>(
        Wd, bd, ws_vals, ws_idx, recon);
}